// Round 10
// baseline (158.177 us; speedup 1.0000x reference)
//
#include <hip/hip_runtime.h>
#include <hip/hip_fp16.h>
#include <cfloat>
#include <math.h>

// Problem constants (fixed by the reference)
#define DIM    256
#define N_TOK  8192
#define N_E    8192
#define NSEG   1024         // 8-col groups per row
// Margin on d = ||e||^2 - 2*dot (bf16 approx pass, fp16-quantized group mins).
// Failure needs Dd(true)-Dd(approx-winner) + 2*quant > margin on a specific
// per-row pair: dot-err diff ~4.3sigma*6.8e-4 ~2.9e-3, fp16 quant 2*1e-3.
// 0.012 ~ 2.4x that. (Passed rounds 7/8/9; 0.016 and 0.008 also passed.)
#define MARGIN 0.012f

typedef __attribute__((ext_vector_type(8))) short bf16x8;
typedef __attribute__((ext_vector_type(4))) float f32x4;
typedef __attribute__((ext_vector_type(8))) unsigned short ushort8;

__device__ __forceinline__ unsigned short f2bf(float f) {      // RNE float->bf16
    unsigned u = __float_as_uint(f);
    unsigned r = u + 0x7fff + ((u >> 16) & 1);
    return (unsigned short)(r >> 16);
}
__device__ __forceinline__ unsigned fkey(float f) {            // monotone f32->u32
    unsigned u = __float_as_uint(f);
    return (u & 0x80000000u) ? ~u : (u | 0x80000000u);
}
__device__ __forceinline__ unsigned short f2h(float f) {       // RNE float->fp16 bits
    const __half h = __float2half(f);
    return *(const unsigned short*)&h;
}
__device__ __forceinline__ float h2f(unsigned short u) {
    __half_raw r; r.x = u;
    return __half2float((__half)r);
}

// ---------------------------------------------------------------------------
// K1: row-wise L2 normalize for BOTH inputs in one launch.
//  - z rows   -> zn fp32 (d_out scratch) + zb bf16 with XOR-CHUNK-SWIZZLE:
//    16-B chunk c (k-range c*8..c*8+7) of row r stored at chunk c ^ (r&31).
//    A linear copy of a 128-row slab into LDS then yields 2-way-free
//    ds_read_b128 fragment reads despite the 512-B row stride.
//  - emb rows -> en fp32 + esw bf16 swizzled into exact MFMA A-fragment order
//    (frag16=row>>4, kc: 512 ushorts at (frag16*8+kc)*512; within:
//    ((k>>3&3)*16 + (row&15))*8 + (k&7)) + e2.
// ---------------------------------------------------------------------------
__global__ __launch_bounds__(256) void l2norm_all(const float* __restrict__ z,
                                                  const float* __restrict__ emb,
                                                  float* __restrict__ zn,
                                                  unsigned short* __restrict__ zb,
                                                  float* __restrict__ en,
                                                  unsigned short* __restrict__ esw,
                                                  float* __restrict__ e2) {
    const int lane = threadIdx.x & 63;
    const bool isE = blockIdx.x < (N_E / 4);
    const int row = (isE ? blockIdx.x : blockIdx.x - N_E / 4) * 4 + (threadIdx.x >> 6);
    const float* in = isE ? emb : z;
    float* out = isE ? en : zn;
    const float4 v = *(const float4*)(in + row * DIM + lane * 4);
    float s = v.x * v.x + v.y * v.y + v.z * v.z + v.w * v.w;
#pragma unroll
    for (int off = 1; off < 64; off <<= 1) s += __shfl_xor(s, off, 64);
    const float inv = 1.0f / fmaxf(sqrtf(s), 1e-12f);
    const float4 o = make_float4(v.x * inv, v.y * inv, v.z * inv, v.w * inv);
    *(float4*)(out + row * DIM + lane * 4) = o;
    ushort4 ob; ob.x = f2bf(o.x); ob.y = f2bf(o.y); ob.z = f2bf(o.z); ob.w = f2bf(o.w);
    const int k0 = lane * 4;
    if (isE) {
        const size_t sidx = ((size_t)((row >> 4) * 8 + (k0 >> 5)) * 64
                             + ((k0 >> 3) & 3) * 16 + (row & 15)) * 8 + (k0 & 7);
        *(ushort4*)(esw + sidx) = ob;
        float q = o.x * o.x + o.y * o.y + o.z * o.z + o.w * o.w;
#pragma unroll
        for (int off = 1; off < 64; off <<= 1) q += __shfl_xor(q, off, 64);
        if (lane == 0) e2[row] = q;
    } else {
        const int c = k0 >> 3;                       // 16-B chunk 0..31
        const int p = c ^ (row & 31);                // bank swizzle
        *(ushort4*)(zb + (size_t)row * DIM + p * 8 + (k0 & 7)) = ob;
    }
}

// ---------------------------------------------------------------------------
// K2: bf16 MFMA distance pass — BARRIER-FREE K-loop. 128x128 block tile,
// 4 waves of 64x64 (4x4 grid of 16x16x32 MFMAs).
//  - The WHOLE 64 KB z tile (128 rows x 256 k, xor-chunk-swizzled) is staged
//    once via global_load_lds (16 instr/wave), ONE __syncthreads, then the
//    8 kc iterations run with no barriers at all: z fragments via 2-way-free
//    ds_read_b128, code fragments direct from the pre-swizzled global buffer
//    (1 KB coalesced global_load_dwordx4/frag), prefetched 2 kc ahead.
//  - Pipe budget/block: LDS 64w+128r KB, VMEM 96 KB, MFMA 128/wave -> floors
//    ~15/10/14 us; no vmcnt(0)-at-barrier serialization (the round-6..9 cap).
// Epilogue: per (row, 8-col group) min -> fp16 segMh[row][1024]; sm buffer
// aliases As after a barrier (LDS stays 64 KB -> 2 blocks/CU).
// ---------------------------------------------------------------------------
__global__ __launch_bounds__(256, 2) void mfma_dist(const unsigned short* __restrict__ zb,
                                                    const unsigned short* __restrict__ esw,
                                                    const float* __restrict__ e2,
                                                    unsigned short* __restrict__ segMh) {
    __shared__ __align__(16) unsigned short As[128 * 256];   // 64 KB z tile
    float* sm = reinterpret_cast<float*>(As);                // aliased epilogue [16][128]

    const int tid  = threadIdx.x;
    const int lane = tid & 63;
    const int wave = tid >> 6;
    const int wm = wave & 1, wn = wave >> 1;
    const int row0 = (blockIdx.x & 63) * 128;
    const int col0 = (blockIdx.x >> 6) * 128;
    const int fr = lane & 15, q = lane >> 4;

    f32x4 acc[4][4];
#pragma unroll
    for (int ci = 0; ci < 4; ci++)
#pragma unroll
        for (int zi = 0; zi < 4; zi++) acc[ci][zi] = (f32x4){0.f, 0.f, 0.f, 0.f};

    // Code fragments: frag16 group aBase+i, address = frag*4096 + kc*512 + lane*8
    const int aBase = (col0 >> 4) + wn * 4;
    auto la = [&](int i, int kc) {
        return *(const bf16x8*)(esw + (size_t)(aBase + i) * 4096 + kc * 512 + lane * 8);
    };
    // z fragment from LDS (xor-chunk-swizzled): row r, chunk c = kc*4+q.
    auto lz = [&](int i, int kc) {
        const int r = wm * 64 + i * 16 + fr;
        const int c = kc * 4 + q;
        return *(const bf16x8*)&As[r * 256 + ((c ^ (r & 31)) * 8)];
    };

    // Early code prefetch (kc 0,1) overlaps the z staging.
    bf16x8 ca[8][4];
#pragma unroll
    for (int i = 0; i < 4; i++) { ca[0][i] = la(i, 0); ca[1][i] = la(i, 1); }

    // Stage the whole z tile: wave stages rows wave*32..+31 (2 rows/instr).
    {
        const unsigned short* gZ = zb + (size_t)(row0 + wave * 32) * DIM;
#pragma unroll
        for (int j = 0; j < 16; j++) {
            __builtin_amdgcn_global_load_lds(
                (const __attribute__((address_space(1))) unsigned int*)(gZ + j * 2 * DIM + lane * 8),
                (__attribute__((address_space(3))) unsigned int*)&As[(wave * 32 + j * 2) * 256],
                16, 0, 0);
        }
    }
    __syncthreads();   // one-time drain; K-loop below has NO barriers

#pragma unroll
    for (int kc = 0; kc < 8; kc++) {
        if (kc + 2 < 8) {
#pragma unroll
            for (int i = 0; i < 4; i++) ca[kc + 2][i] = la(i, kc + 2);
        }
        bf16x8 zfr[4];
#pragma unroll
        for (int i = 0; i < 4; i++) zfr[i] = lz(i, kc);
#pragma unroll
        for (int ci = 0; ci < 4; ci++)
#pragma unroll
            for (int zi = 0; zi < 4; zi++)
                acc[ci][zi] = __builtin_amdgcn_mfma_f32_16x16x32_bf16(ca[kc][ci], zfr[zi], acc[ci][zi], 0, 0, 0);
    }

    // Epilogue. C/D: m (code) = (lane>>4)*4 + reg, n (z row) = lane&15.
    float4 e2q[4];
#pragma unroll
    for (int ci = 0; ci < 4; ci++)
        e2q[ci] = *(const float4*)&e2[col0 + wn * 64 + ci * 16 + q * 4];
    __syncthreads();   // all As reads done; safe to reuse as sm
#pragma unroll
    for (int ci = 0; ci < 4; ci++) {
#pragma unroll
        for (int zi = 0; zi < 4; zi++) {
            const float t0 = fmaf(-2.0f, acc[ci][zi][0], e2q[ci].x);
            const float t1 = fmaf(-2.0f, acc[ci][zi][1], e2q[ci].y);
            const float t2 = fmaf(-2.0f, acc[ci][zi][2], e2q[ci].z);
            const float t3 = fmaf(-2.0f, acc[ci][zi][3], e2q[ci].w);
            float mm = fminf(fminf(t0, t1), fminf(t2, t3));   // min over 4 codes (regs)
            mm = fminf(mm, __shfl_xor(mm, 16, 64));           // pair quads: 8-code min
            // q==0 holds codes 0..7 min; q==2 holds codes 8..15 min
            if (q == 0) sm[(wn * 8 + ci * 2 + 0) * 128 + wm * 64 + zi * 16 + fr] = mm;
            if (q == 2) sm[(wn * 8 + ci * 2 + 1) * 128 + wm * 64 + zi * 16 + fr] = mm;
        }
    }
    __syncthreads();
    // Store 16 segs x 128 rows as fp16, coalesced: thread t -> row t&127,
    // 8 consecutive segs (part = t>>7).
    {
        const int rl = tid & 127, part = tid >> 7;
        ushort8 o8;
#pragma unroll
        for (int j = 0; j < 8; j++) o8[j] = f2h(sm[(part * 8 + j) * 128 + rl]);
        *(ushort8*)&segMh[(size_t)(row0 + rl) * NSEG + (col0 >> 3) + part * 8] = o8;
    }
}

// ---------------------------------------------------------------------------
// K3 (fused select+rescore+gather): one WAVE per row, ZERO atomics.
//  1. read 1024 fp16 group-mins (2 KB contiguous), shuffle-min -> threshold
//  2. ballot-flag 8-col groups within m+MARGIN (winner always self-flags)
//  3. wave-uniform bit-walk; exact fp32 rescore (16 lanes split the 256-dim
//     dot, 4 cols per pass, 2 passes/group); packed (key|col) running min
//     -> exact argmin with lowest-index tie-break (matches jnp.argmin)
//  4. gather en[idx] -> z_q, per-row loss partial to pl[row], index out.
// ---------------------------------------------------------------------------
__global__ __launch_bounds__(256) void select_rescore(const unsigned short* __restrict__ segMh,
                                                      const float* __restrict__ en,
                                                      const float* __restrict__ e2,
                                                      float* zq,        // d_out: z_norm in / z_q out
                                                      float* out_base,  // d_out
                                                      float* __restrict__ pl) {
    const int lane = threadIdx.x & 63;
    const int row  = (blockIdx.x << 2) + (threadIdx.x >> 6);
    const unsigned short* ph = segMh + (size_t)row * NSEG + lane * 16;
    const ushort8 u0 = *(const ushort8*)ph;
    const ushort8 u1 = *(const ushort8*)(ph + 8);
    float vv[16];
#pragma unroll
    for (int j = 0; j < 8; j++) { vv[j] = h2f(u0[j]); vv[8 + j] = h2f(u1[j]); }
    float m = vv[0];
#pragma unroll
    for (int j = 1; j < 16; j++) m = fminf(m, vv[j]);
#pragma unroll
    for (int off = 1; off < 64; off <<= 1) m = fminf(m, __shfl_xor(m, off, 64));
    const float thr = m + MARGIN;

    // z row in 16-lane-split layout for the rescore dots (shared by all groups)
    const int q = lane >> 4, f = lane & 15;
    const float4* zp = (const float4*)(zq + (size_t)row * DIM);
    float4 z4[4];
#pragma unroll
    for (int j = 0; j < 4; j++) z4[j] = zp[j * 16 + f];

    unsigned long long pk = ~0ull;
#pragma unroll
    for (int j = 0; j < 16; j++) {
        unsigned long long bal = __ballot(vv[j] <= thr);   // wave-uniform
        while (bal) {
            const int l = __ffsll(bal) - 1;
            bal &= bal - 1;
            const int seg = l * 16 + j;                    // lane l holds segs l*16+j
#pragma unroll
            for (int g = 0; g < 2; g++) {
                const int col = seg * 8 + g * 4 + q;
                const float4* ep = (const float4*)(en + (size_t)col * DIM);
                float s = 0.f;
#pragma unroll
                for (int jj = 0; jj < 4; jj++) {
                    const float4 ev = ep[jj * 16 + f];
                    s = fmaf(z4[jj].x, ev.x, s); s = fmaf(z4[jj].y, ev.y, s);
                    s = fmaf(z4[jj].z, ev.z, s); s = fmaf(z4[jj].w, ev.w, s);
                }
#pragma unroll
                for (int off = 1; off < 16; off <<= 1) s += __shfl_xor(s, off, 64);
                const float d = fmaf(-2.0f, s, e2[col]);
                const unsigned long long key =
                    ((unsigned long long)fkey(d) << 32) | (unsigned)col;
                if (key < pk) pk = key;
            }
        }
    }
#pragma unroll
    for (int off = 16; off < 64; off <<= 1) {               // merge the 4 quads
        const unsigned long long o = __shfl_xor(pk, off, 64);
        if (o < pk) pk = o;
    }
    const int i = (int)(pk & 0xffffffffu);

    // Gather z_q, loss partial, index (plain stores, no atomics).
    const float4 qv = *(const float4*)(en + (size_t)i * DIM + lane * 4);
    const float4 zv = *(const float4*)(zq + (size_t)row * DIM + lane * 4);
    const float dx = qv.x - zv.x, dy = qv.y - zv.y, dz = qv.z - zv.z, dw = qv.w - zv.w;
    float s = dx * dx + dy * dy + dz * dz + dw * dw;
    *(float4*)(zq + (size_t)row * DIM + lane * 4) = qv;
#pragma unroll
    for (int off = 1; off < 64; off <<= 1) s += __shfl_xor(s, off, 64);
    if (lane == 0) {
        pl[row] = s;
        out_base[N_TOK * DIM + 1 + row] = (float)i;
    }
}

// ---------------------------------------------------------------------------
// K4: reduce 8192 per-row loss partials -> loss = 1.25 * sum / (8*1024*256).
// ---------------------------------------------------------------------------
__global__ __launch_bounds__(1024) void finalize_loss(const float* __restrict__ pl,
                                                      float* __restrict__ out) {
    __shared__ float sw[16];
    const int t = threadIdx.x;
    float s = 0.f;
#pragma unroll
    for (int j = 0; j < 8; j++) s += pl[t + j * 1024];
#pragma unroll
    for (int off = 1; off < 64; off <<= 1) s += __shfl_xor(s, off, 64);
    if ((t & 63) == 0) sw[t >> 6] = s;
    __syncthreads();
    if (t < 16) {
        float v = sw[t];
#pragma unroll
        for (int off = 1; off < 16; off <<= 1) v += __shfl_xor(v, off, 64);
        if (t == 0) out[N_TOK * DIM] = v * (1.25f / 2097152.0f);
    }
}

// ---------------------------------------------------------------------------
extern "C" void kernel_launch(void* const* d_in, const int* in_sizes, int n_in,
                              void* d_out, int out_size, void* d_ws, size_t ws_size,
                              hipStream_t stream) {
    const float* z   = (const float*)d_in[0];   // [8,1024,256] fp32
    const float* emb = (const float*)d_in[1];   // [8192,256] fp32
    float* out = (float*)d_out;                 // z_q[2097152] | loss[1] | idx[8192]
    char* ws = (char*)d_ws;

    // ws layout (byte offsets; total ~33.6 MB)
    float*          en    = (float*)(ws);                      //  8 MiB fp32 codes (normalized)
    unsigned short* esw   = (unsigned short*)(ws + 8388608);   //  4 MiB bf16 codes (frag-swizzled)
    unsigned short* zb    = (unsigned short*)(ws + 12582912);  //  4 MiB bf16 z (xor-chunk-swizzled)
    float*          e2    = (float*)(ws + 16777216);           // 32 KiB ||e||^2
    unsigned short* segMh = (unsigned short*)(ws + 16809984);  // 16 MiB fp16 [8192][1024]
    float*          pl    = (float*)(ws + 33587200);           // 32 KiB per-row loss partials

    // 1) normalize both inputs (emb -> en/esw/e2; z -> d_out z_q region + zb)
    l2norm_all<<<(N_E + N_TOK) / 4, 256, 0, stream>>>(z, emb, out, zb, en, esw, e2);
    // 2) bf16 MFMA approx distances (barrier-free K-loop) -> fp16 group mins
    mfma_dist<<<64 * 64, 256, 0, stream>>>(zb, esw, e2, segMh);
    // 3) fused select + exact rescore + gather (wave per row, no atomics)
    select_rescore<<<N_TOK / 4, 256, 0, stream>>>(segMh, en, e2, out, out, pl);
    // 4) reduce loss partials
    finalize_loss<<<1, 1024, 0, stream>>>(pl, out);
}

// Round 11
// 137.050 us; speedup vs baseline: 1.1542x; 1.1542x over previous
//
#include <hip/hip_runtime.h>
#include <hip/hip_fp16.h>
#include <cfloat>
#include <math.h>

// Problem constants (fixed by the reference)
#define DIM    256
#define N_TOK  8192
#define N_E    8192
#define NSEG   1024         // 8-col groups per row
// Margin on d = ||e||^2 - 2*dot (bf16 approx pass, fp16-quantized group mins).
// Failure needs Dd(true)-Dd(approx-winner) + 2*quant > margin on a specific
// per-row pair: dot-err diff ~4.3sigma*6.8e-4 ~2.9e-3, fp16 quant 2*1e-3.
// 0.012 ~ 2.4x that. (Passed rounds 7-10; 0.016 and 0.008 also passed.)
#define MARGIN 0.012f

typedef __attribute__((ext_vector_type(8))) short bf16x8;
typedef __attribute__((ext_vector_type(4))) float f32x4;
typedef __attribute__((ext_vector_type(8))) unsigned short ushort8;

__device__ __forceinline__ unsigned short f2bf(float f) {      // RNE float->bf16
    unsigned u = __float_as_uint(f);
    unsigned r = u + 0x7fff + ((u >> 16) & 1);
    return (unsigned short)(r >> 16);
}
__device__ __forceinline__ unsigned fkey(float f) {            // monotone f32->u32
    unsigned u = __float_as_uint(f);
    return (u & 0x80000000u) ? ~u : (u | 0x80000000u);
}
__device__ __forceinline__ unsigned short f2h(float f) {       // RNE float->fp16 bits
    const __half h = __float2half(f);
    return *(const unsigned short*)&h;
}
__device__ __forceinline__ float h2f(unsigned short u) {
    __half_raw r; r.x = u;
    return __half2float((__half)r);
}

// ---------------------------------------------------------------------------
// K1: row-wise L2 normalize for BOTH inputs in one launch.
//  - z rows   -> zn fp32 (d_out scratch) + zb bf16 PLAIN row-major (the LDS
//    staging swizzle is applied via per-lane global addresses in mfma_dist).
//  - emb rows -> en fp32 + esw bf16 swizzled into exact MFMA A-fragment order
//    (frag16=row>>4, kc: 512 ushorts at (frag16*8+kc)*512; within:
//    ((k>>3&3)*16 + (row&15))*8 + (k&7)) + e2.
// ---------------------------------------------------------------------------
__global__ __launch_bounds__(256) void l2norm_all(const float* __restrict__ z,
                                                  const float* __restrict__ emb,
                                                  float* __restrict__ zn,
                                                  unsigned short* __restrict__ zb,
                                                  float* __restrict__ en,
                                                  unsigned short* __restrict__ esw,
                                                  float* __restrict__ e2) {
    const int lane = threadIdx.x & 63;
    const bool isE = blockIdx.x < (N_E / 4);
    const int row = (isE ? blockIdx.x : blockIdx.x - N_E / 4) * 4 + (threadIdx.x >> 6);
    const float* in = isE ? emb : z;
    float* out = isE ? en : zn;
    const float4 v = *(const float4*)(in + row * DIM + lane * 4);
    float s = v.x * v.x + v.y * v.y + v.z * v.z + v.w * v.w;
#pragma unroll
    for (int off = 1; off < 64; off <<= 1) s += __shfl_xor(s, off, 64);
    const float inv = 1.0f / fmaxf(sqrtf(s), 1e-12f);
    const float4 o = make_float4(v.x * inv, v.y * inv, v.z * inv, v.w * inv);
    *(float4*)(out + row * DIM + lane * 4) = o;
    ushort4 ob; ob.x = f2bf(o.x); ob.y = f2bf(o.y); ob.z = f2bf(o.z); ob.w = f2bf(o.w);
    const int k0 = lane * 4;
    if (isE) {
        const size_t sidx = ((size_t)((row >> 4) * 8 + (k0 >> 5)) * 64
                             + ((k0 >> 3) & 3) * 16 + (row & 15)) * 8 + (k0 & 7);
        *(ushort4*)(esw + sidx) = ob;
        float q = o.x * o.x + o.y * o.y + o.z * o.z + o.w * o.w;
#pragma unroll
        for (int off = 1; off < 64; off <<= 1) q += __shfl_xor(q, off, 64);
        if (lane == 0) e2[row] = q;
    } else {
        *(ushort4*)(zb + (size_t)row * DIM + k0) = ob;
    }
}

// ---------------------------------------------------------------------------
// K2: bf16 MFMA distance pass — hybrid feed, BK=64 double-buffered staging,
// FOUR barriers/block (vs 16 in the 54.3us version). 128x128 block tile,
// 4 waves of 64x64 (4x4 grid of 16x16x32 MFMAs).
//  - z rows: staged into As[2][128 rows x 8 chunks] (16 KB/buffer). Stage
//    pair p+1 issues right after the barrier and has 2 kc of MFMA (~620 cyc
//    > L2 latency) in flight before its drain -> barrier drains ~free.
//    XOR slot swizzle baked into the PER-LANE GLOBAL addresses of
//    global_load_lds (cxor const per lane); fragment ds_read_b128 at slot
//    (h*4+q)^(fr&7) -> exactly 8 lanes/16B-slot = conflict-free.
//  - codes: direct from the fragment-order global buffer, rolling 2-kc-deep
//    register prefetch (live window 3 -> fits ~100 VGPRs, 3 waves/SIMD).
// Epilogue: per (row, 8-col group) min -> fp16 segMh[row][1024]; sm aliases As.
// ---------------------------------------------------------------------------
__global__ __launch_bounds__(256, 2) void mfma_dist(const unsigned short* __restrict__ zb,
                                                    const unsigned short* __restrict__ esw,
                                                    const float* __restrict__ e2,
                                                    unsigned short* __restrict__ segMh) {
    __shared__ __align__(16) unsigned short As[2][128 * 64];   // 2 x 16 KB z chunk-pair
    float* sm = reinterpret_cast<float*>(As);                  // aliased epilogue [16][128]

    const int tid  = threadIdx.x;
    const int lane = tid & 63;
    const int wave = tid >> 6;
    const int wm = wave & 1, wn = wave >> 1;
    const int row0 = (blockIdx.x & 63) * 128;
    const int col0 = (blockIdx.x >> 6) * 128;
    const int fr = lane & 15, q = lane >> 4;

    f32x4 acc[4][4];
#pragma unroll
    for (int ci = 0; ci < 4; ci++)
#pragma unroll
        for (int zi = 0; zi < 4; zi++) acc[ci][zi] = (f32x4){0.f, 0.f, 0.f, 0.f};

    // Code fragments: frag16 group aBase+i, address = frag*4096 + kc*512 + lane*8
    const int aBase = (col0 >> 4) + wn * 4;
    auto la = [&](int i, int kc) {
        return *(const bf16x8*)(esw + (size_t)(aBase + i) * 4096 + kc * 512 + lane * 8);
    };
    // z staging, pair p (k in [p*64, p*64+64)): wave stages rows wave*32..+31,
    // 4 instrs of 1 KB; lane -> row (lane>>3) of the 8-row slab, slot lane&7.
    // Global chunk fetched = p*8 + (slot ^ (r&7)); r&7 == (lane>>3)&7 here.
    const int cxor = (lane & 7) ^ ((lane >> 3) & 7);            // const per lane
    const unsigned short* gZ = zb + (size_t)(row0 + wave * 32 + (lane >> 3)) * DIM + cxor * 8;
    auto stage = [&](int buf, int p) {
#pragma unroll
        for (int j = 0; j < 4; j++) {
            __builtin_amdgcn_global_load_lds(
                (const __attribute__((address_space(1))) unsigned int*)(gZ + (size_t)j * 8 * DIM + p * 64),
                (__attribute__((address_space(3))) unsigned int*)&As[buf][(wave * 32 + j * 8) * 64],
                16, 0, 0);
        }
    };
    // z fragment from LDS: kc = 2p+h, logical chunk h*4+q, slot ^= (fr&7).
    auto lz = [&](int buf, int i, int h) {
        const int r = wm * 64 + i * 16 + fr;
        const int slot = (h * 4 + q) ^ (fr & 7);
        return *(const bf16x8*)&As[buf][r * 64 + slot * 8];
    };

    bf16x8 ca[8][4];
#pragma unroll
    for (int i = 0; i < 4; i++) { ca[0][i] = la(i, 0); ca[1][i] = la(i, 1); }
    stage(0, 0);

#pragma unroll
    for (int p = 0; p < 4; p++) {
        __syncthreads();                 // drains stage(p) (2 kc of compute in flight)
        if (p < 3) stage((p + 1) & 1, p + 1);
#pragma unroll
        for (int h = 0; h < 2; h++) {
            const int kc = 2 * p + h;
            if (kc + 2 < 8) {
#pragma unroll
                for (int i = 0; i < 4; i++) ca[kc + 2][i] = la(i, kc + 2);
            }
            bf16x8 zfr[4];
#pragma unroll
            for (int i = 0; i < 4; i++) zfr[i] = lz(p & 1, i, h);
#pragma unroll
            for (int ci = 0; ci < 4; ci++)
#pragma unroll
                for (int zi = 0; zi < 4; zi++)
                    acc[ci][zi] = __builtin_amdgcn_mfma_f32_16x16x32_bf16(ca[kc][ci], zfr[zi], acc[ci][zi], 0, 0, 0);
        }
    }

    // Epilogue. C/D: m (code) = (lane>>4)*4 + reg, n (z row) = lane&15.
    float4 e2q[4];
#pragma unroll
    for (int ci = 0; ci < 4; ci++)
        e2q[ci] = *(const float4*)&e2[col0 + wn * 64 + ci * 16 + q * 4];
    __syncthreads();   // all As reads done; safe to reuse as sm
#pragma unroll
    for (int ci = 0; ci < 4; ci++) {
#pragma unroll
        for (int zi = 0; zi < 4; zi++) {
            const float t0 = fmaf(-2.0f, acc[ci][zi][0], e2q[ci].x);
            const float t1 = fmaf(-2.0f, acc[ci][zi][1], e2q[ci].y);
            const float t2 = fmaf(-2.0f, acc[ci][zi][2], e2q[ci].z);
            const float t3 = fmaf(-2.0f, acc[ci][zi][3], e2q[ci].w);
            float mm = fminf(fminf(t0, t1), fminf(t2, t3));   // min over 4 codes (regs)
            mm = fminf(mm, __shfl_xor(mm, 16, 64));           // pair quads: 8-code min
            // q==0 holds codes 0..7 min; q==2 holds codes 8..15 min
            if (q == 0) sm[(wn * 8 + ci * 2 + 0) * 128 + wm * 64 + zi * 16 + fr] = mm;
            if (q == 2) sm[(wn * 8 + ci * 2 + 1) * 128 + wm * 64 + zi * 16 + fr] = mm;
        }
    }
    __syncthreads();
    // Store 16 segs x 128 rows as fp16, coalesced: thread t -> row t&127,
    // 8 consecutive segs (part = t>>7).
    {
        const int rl = tid & 127, part = tid >> 7;
        ushort8 o8;
#pragma unroll
        for (int j = 0; j < 8; j++) o8[j] = f2h(sm[(part * 8 + j) * 128 + rl]);
        *(ushort8*)&segMh[(size_t)(row0 + rl) * NSEG + (col0 >> 3) + part * 8] = o8;
    }
}

// ---------------------------------------------------------------------------
// K3 (fused select+rescore+gather): one WAVE per row, ZERO atomics.
//  1. read 1024 fp16 group-mins (2 KB contiguous), shuffle-min -> threshold
//  2. ballot-flag 8-col groups within m+MARGIN (winner always self-flags)
//  3. wave-uniform bit-walk; exact fp32 rescore (16 lanes split the 256-dim
//     dot, 4 cols per pass, 2 passes/group); packed (key|col) running min
//     -> exact argmin with lowest-index tie-break (matches jnp.argmin)
//  4. gather en[idx] -> z_q, per-row loss partial to pl[row], index out.
// ---------------------------------------------------------------------------
__global__ __launch_bounds__(256) void select_rescore(const unsigned short* __restrict__ segMh,
                                                      const float* __restrict__ en,
                                                      const float* __restrict__ e2,
                                                      float* zq,        // d_out: z_norm in / z_q out
                                                      float* out_base,  // d_out
                                                      float* __restrict__ pl) {
    const int lane = threadIdx.x & 63;
    const int row  = (blockIdx.x << 2) + (threadIdx.x >> 6);
    const unsigned short* ph = segMh + (size_t)row * NSEG + lane * 16;
    const ushort8 u0 = *(const ushort8*)ph;
    const ushort8 u1 = *(const ushort8*)(ph + 8);
    float vv[16];
#pragma unroll
    for (int j = 0; j < 8; j++) { vv[j] = h2f(u0[j]); vv[8 + j] = h2f(u1[j]); }
    float m = vv[0];
#pragma unroll
    for (int j = 1; j < 16; j++) m = fminf(m, vv[j]);
#pragma unroll
    for (int off = 1; off < 64; off <<= 1) m = fminf(m, __shfl_xor(m, off, 64));
    const float thr = m + MARGIN;

    // z row in 16-lane-split layout for the rescore dots (shared by all groups)
    const int q = lane >> 4, f = lane & 15;
    const float4* zp = (const float4*)(zq + (size_t)row * DIM);
    float4 z4[4];
#pragma unroll
    for (int j = 0; j < 4; j++) z4[j] = zp[j * 16 + f];

    unsigned long long pk = ~0ull;
#pragma unroll
    for (int j = 0; j < 16; j++) {
        unsigned long long bal = __ballot(vv[j] <= thr);   // wave-uniform
        while (bal) {
            const int l = __ffsll(bal) - 1;
            bal &= bal - 1;
            const int seg = l * 16 + j;                    // lane l holds segs l*16+j
#pragma unroll
            for (int g = 0; g < 2; g++) {
                const int col = seg * 8 + g * 4 + q;
                const float4* ep = (const float4*)(en + (size_t)col * DIM);
                float s = 0.f;
#pragma unroll
                for (int jj = 0; jj < 4; jj++) {
                    const float4 ev = ep[jj * 16 + f];
                    s = fmaf(z4[jj].x, ev.x, s); s = fmaf(z4[jj].y, ev.y, s);
                    s = fmaf(z4[jj].z, ev.z, s); s = fmaf(z4[jj].w, ev.w, s);
                }
#pragma unroll
                for (int off = 1; off < 16; off <<= 1) s += __shfl_xor(s, off, 64);
                const float d = fmaf(-2.0f, s, e2[col]);
                const unsigned long long key =
                    ((unsigned long long)fkey(d) << 32) | (unsigned)col;
                if (key < pk) pk = key;
            }
        }
    }
#pragma unroll
    for (int off = 16; off < 64; off <<= 1) {               // merge the 4 quads
        const unsigned long long o = __shfl_xor(pk, off, 64);
        if (o < pk) pk = o;
    }
    const int i = (int)(pk & 0xffffffffu);

    // Gather z_q, loss partial, index (plain stores, no atomics).
    const float4 qv = *(const float4*)(en + (size_t)i * DIM + lane * 4);
    const float4 zv = *(const float4*)(zq + (size_t)row * DIM + lane * 4);
    const float dx = qv.x - zv.x, dy = qv.y - zv.y, dz = qv.z - zv.z, dw = qv.w - zv.w;
    float s = dx * dx + dy * dy + dz * dz + dw * dw;
    *(float4*)(zq + (size_t)row * DIM + lane * 4) = qv;
#pragma unroll
    for (int off = 1; off < 64; off <<= 1) s += __shfl_xor(s, off, 64);
    if (lane == 0) {
        pl[row] = s;
        out_base[N_TOK * DIM + 1 + row] = (float)i;
    }
}

// ---------------------------------------------------------------------------
// K4: reduce 8192 per-row loss partials -> loss = 1.25 * sum / (8*1024*256).
// ---------------------------------------------------------------------------
__global__ __launch_bounds__(1024) void finalize_loss(const float* __restrict__ pl,
                                                      float* __restrict__ out) {
    __shared__ float sw[16];
    const int t = threadIdx.x;
    float s = 0.f;
#pragma unroll
    for (int j = 0; j < 8; j++) s += pl[t + j * 1024];
#pragma unroll
    for (int off = 1; off < 64; off <<= 1) s += __shfl_xor(s, off, 64);
    if ((t & 63) == 0) sw[t >> 6] = s;
    __syncthreads();
    if (t < 16) {
        float v = sw[t];
#pragma unroll
        for (int off = 1; off < 16; off <<= 1) v += __shfl_xor(v, off, 64);
        if (t == 0) out[N_TOK * DIM] = v * (1.25f / 2097152.0f);
    }
}

// ---------------------------------------------------------------------------
extern "C" void kernel_launch(void* const* d_in, const int* in_sizes, int n_in,
                              void* d_out, int out_size, void* d_ws, size_t ws_size,
                              hipStream_t stream) {
    const float* z   = (const float*)d_in[0];   // [8,1024,256] fp32
    const float* emb = (const float*)d_in[1];   // [8192,256] fp32
    float* out = (float*)d_out;                 // z_q[2097152] | loss[1] | idx[8192]
    char* ws = (char*)d_ws;

    // ws layout (byte offsets; total ~33.6 MB)
    float*          en    = (float*)(ws);                      //  8 MiB fp32 codes (normalized)
    unsigned short* esw   = (unsigned short*)(ws + 8388608);   //  4 MiB bf16 codes (frag-swizzled)
    unsigned short* zb    = (unsigned short*)(ws + 12582912);  //  4 MiB bf16 z (plain row-major)
    float*          e2    = (float*)(ws + 16777216);           // 32 KiB ||e||^2
    unsigned short* segMh = (unsigned short*)(ws + 16809984);  // 16 MiB fp16 [8192][1024]
    float*          pl    = (float*)(ws + 33587200);           // 32 KiB per-row loss partials

    // 1) normalize both inputs (emb -> en/esw/e2; z -> d_out z_q region + zb)
    l2norm_all<<<(N_E + N_TOK) / 4, 256, 0, stream>>>(z, emb, out, zb, en, esw, e2);
    // 2) bf16 MFMA approx distances (BK=64 dbuf hybrid, 4 barriers) -> fp16 mins
    mfma_dist<<<64 * 64, 256, 0, stream>>>(zb, esw, e2, segMh);
    // 3) fused select + exact rescore + gather (wave per row, no atomics)
    select_rescore<<<N_TOK / 4, 256, 0, stream>>>(segMh, en, e2, out, out, pl);
    // 4) reduce loss partials
    finalize_loss<<<1, 1024, 0, stream>>>(pl, out);
}